// Round 1
// baseline (131.402 us; speedup 1.0000x reference)
//
#include <hip/hip_runtime.h>
#include <hip/hip_bf16.h>

// Problem constants (from reference)
#define BATCH 512
#define NKER  256
#define LEN   1000      // embedding input length
#define EDIM  3
#define OUTN  128
#define NROWS (BATCH * NKER)      // 131072
#define NF4   (LEN / 4)           // 250 float4 per row
#define FC_IN (EDIM * NKER)       // 768

// ---------------- Stage 1: y[b,k,e] = sum_l x[b,k,l] * W_emb[e,l] ----------
// One wave (64 lanes) per (b,k) row. float4 loads, W_emb in LDS, shfl reduce.
__global__ __launch_bounds__(256) void stage1_emb(const float* __restrict__ x,
                                                  const float* __restrict__ W_emb,
                                                  float* __restrict__ y) {
    __shared__ float w_s[EDIM][LEN];   // 12 KB; row stride 4000 B (16B-aligned)
    for (int i = threadIdx.x; i < EDIM * LEN; i += 256) {
        w_s[i / LEN][i % LEN] = W_emb[i];
    }
    __syncthreads();

    const int wave = threadIdx.x >> 6;
    const int lane = threadIdx.x & 63;
    const int rows_per_iter = gridDim.x * 4;

    for (int row = blockIdx.x * 4 + wave; row < NROWS; row += rows_per_iter) {
        const float4* __restrict__ xr =
            reinterpret_cast<const float4*>(x + (size_t)row * LEN);
        float s0 = 0.f, s1 = 0.f, s2 = 0.f;
        for (int f = lane; f < NF4; f += 64) {
            float4 xv = xr[f];                  // coalesced: 16B/lane
            const int l = f * 4;
            float4 w0 = *reinterpret_cast<const float4*>(&w_s[0][l]);
            float4 w1 = *reinterpret_cast<const float4*>(&w_s[1][l]);
            float4 w2 = *reinterpret_cast<const float4*>(&w_s[2][l]);
            s0 += xv.x * w0.x + xv.y * w0.y + xv.z * w0.z + xv.w * w0.w;
            s1 += xv.x * w1.x + xv.y * w1.y + xv.z * w1.z + xv.w * w1.w;
            s2 += xv.x * w2.x + xv.y * w2.y + xv.z * w2.z + xv.w * w2.w;
        }
        // 64-lane butterfly reduction
        #pragma unroll
        for (int m = 32; m >= 1; m >>= 1) {
            s0 += __shfl_xor(s0, m);
            s1 += __shfl_xor(s1, m);
            s2 += __shfl_xor(s2, m);
        }
        if (lane == 0) {
            float* yr = y + (size_t)row * EDIM;   // [B, K, 3] row-major == reshape(B, 3K)
            yr[0] = s0;
            yr[1] = s1;
            yr[2] = s2;
        }
    }
}

// ---------------- Stage 1.5: transpose W_fc2 [OUT, 768] -> Wt [768, OUT] ----
__global__ __launch_bounds__(256) void transpose_wfc2(const float* __restrict__ W,
                                                      float* __restrict__ Wt) {
    int idx = blockIdx.x * 256 + threadIdx.x;   // index into Wt (coalesced write)
    if (idx < FC_IN * OUTN) {
        int j = idx >> 7;          // 0..767
        int o = idx & (OUTN - 1);  // 0..127
        Wt[idx] = W[o * FC_IN + j];
    }
}

// ---------------- Stage 2: out[b,o] = sum_j y[b,j] * Wt[j,o] + bias[o] ------
__global__ __launch_bounds__(128) void stage2_fc(const float* __restrict__ y,
                                                 const float* __restrict__ Wt,
                                                 const float* __restrict__ bias,
                                                 float* __restrict__ out) {
    __shared__ float ys[FC_IN];
    const int b = blockIdx.x;
    for (int i = threadIdx.x; i < FC_IN; i += 128) ys[i] = y[(size_t)b * FC_IN + i];
    __syncthreads();

    const int o = threadIdx.x;
    float acc = bias[o];
    #pragma unroll 8
    for (int j = 0; j < FC_IN; ++j) {
        acc += ys[j] * Wt[j * OUTN + o];   // ys[j] broadcast; Wt coalesced across lanes
    }
    out[(size_t)b * OUTN + o] = acc;
}

extern "C" void kernel_launch(void* const* d_in, const int* in_sizes, int n_in,
                              void* d_out, int out_size, void* d_ws, size_t ws_size,
                              hipStream_t stream) {
    const float* x     = (const float*)d_in[0];   // [512, 256, 1000]
    const float* W_emb = (const float*)d_in[1];   // [3, 1000]
    const float* W_fc2 = (const float*)d_in[2];   // [128, 768]
    const float* b_fc2 = (const float*)d_in[3];   // [128]
    float* out = (float*)d_out;                   // [512, 128]

    // Workspace layout: y [131072*3] floats, then Wt [768*128] floats
    float* y  = (float*)d_ws;
    float* Wt = y + (size_t)NROWS * EDIM;

    // Stage 1: 2048 blocks x 256 threads (4 waves/block, grid-stride)
    stage1_emb<<<2048, 256, 0, stream>>>(x, W_emb, y);

    // Transpose fc2 weight (runs concurrently-safe: separate ws region, same stream order)
    transpose_wfc2<<<(FC_IN * OUTN + 255) / 256, 256, 0, stream>>>(W_fc2, Wt);

    // Stage 2: one block per batch row
    stage2_fc<<<BATCH, 128, 0, stream>>>(y, Wt, b_fc2, out);
}